// Round 1
// baseline (212.806 us; speedup 1.0000x reference)
//
#include <hip/hip_runtime.h>
#include <math.h>

// Problem constants (hardcoded from reference)
constexpr int NB = 8;
constexpr int LL = 4096;
constexpr int CC = 256;
constexpr int GG = 8;
constexpr int KS = 3;
constexpr int GC = 32;   // CC/GG
constexpr int GK = 24;   // GG*KS
constexpr int MM = NB * LL;  // 32768 rows

// ---------------------------------------------------------------------------
// K1/K4: fp32 GEMM  C[M,256] = A[M,256] @ B[256,256] + bias[256]
// tile 128x64, BK=16, 256 threads, 8x4 acc per thread
// ---------------------------------------------------------------------------
__global__ __launch_bounds__(256) void gemm_bias(
    const float* __restrict__ A, const float* __restrict__ B,
    const float* __restrict__ bias, float* __restrict__ Cm)
{
    __shared__ float As[16][128];
    __shared__ float Bs[16][64];

    const int t = threadIdx.x;
    const int tx = t & 15, ty = t >> 4;
    const int rowBase = blockIdx.y << 7;   // *128
    const int colBase = blockIdx.x << 6;   // *64

    // A-tile load mapping: thread covers row ar, k-segment [ak, ak+8)
    const int ar = t >> 1;          // 0..127
    const int ak = (t & 1) << 3;    // 0 or 8
    // B-tile load mapping: one float4 per thread
    const int bk = t >> 4;          // 0..15
    const int bc = (t & 15) << 2;   // 0..60

    const float* Aptr = A + (size_t)(rowBase + ar) * CC + ak;
    const float* Bptr = B + (size_t)bk * CC + colBase + bc;

    float acc[8][4];
#pragma unroll
    for (int i = 0; i < 8; ++i)
#pragma unroll
        for (int j = 0; j < 4; ++j) acc[i][j] = 0.f;

    for (int k0 = 0; k0 < CC; k0 += 16) {
        float4 a0 = *(const float4*)(Aptr + k0);
        float4 a1 = *(const float4*)(Aptr + k0 + 4);
        float4 b0 = *(const float4*)(Bptr + (size_t)k0 * CC);
        As[ak + 0][ar] = a0.x; As[ak + 1][ar] = a0.y;
        As[ak + 2][ar] = a0.z; As[ak + 3][ar] = a0.w;
        As[ak + 4][ar] = a1.x; As[ak + 5][ar] = a1.y;
        As[ak + 6][ar] = a1.z; As[ak + 7][ar] = a1.w;
        *(float4*)&Bs[bk][bc] = b0;
        __syncthreads();
#pragma unroll
        for (int kk = 0; kk < 16; ++kk) {
            float4 av0 = *(const float4*)&As[kk][ty * 8];
            float4 av1 = *(const float4*)&As[kk][ty * 8 + 4];
            float4 bv  = *(const float4*)&Bs[kk][tx * 4];
            float a[8] = {av0.x, av0.y, av0.z, av0.w, av1.x, av1.y, av1.z, av1.w};
            float b[4] = {bv.x, bv.y, bv.z, bv.w};
#pragma unroll
            for (int i = 0; i < 8; ++i)
#pragma unroll
                for (int j = 0; j < 4; ++j)
                    acc[i][j] = fmaf(a[i], b[j], acc[i][j]);
        }
        __syncthreads();
    }

    const int cb = colBase + tx * 4;
    const float b0 = bias[cb + 0], b1 = bias[cb + 1];
    const float b2 = bias[cb + 2], b3 = bias[cb + 3];
#pragma unroll
    for (int i = 0; i < 8; ++i) {
        const int row = rowBase + ty * 8 + i;
        float4 v = make_float4(acc[i][0] + b0, acc[i][1] + b1,
                               acc[i][2] + b2, acc[i][3] + b3);
        *(float4*)&Cm[(size_t)row * CC + cb] = v;
    }
}

// ---------------------------------------------------------------------------
// K2: depthwise conv(K=3, zero pad) + LayerNorm(C) + exact GELU
// one wave (64 lanes) per (n,l) row; 4 channels per lane
// ---------------------------------------------------------------------------
__global__ __launch_bounds__(256) void conv_ln_gelu(
    const float* __restrict__ x, const float* __restrict__ cw,
    const float* __restrict__ cbias, const float* __restrict__ lng,
    const float* __restrict__ lnb, float* __restrict__ xf)
{
    const int wave = threadIdx.x >> 6;
    const int lane = threadIdx.x & 63;
    const int nl = (blockIdx.x << 2) + wave;
    const int l = nl & (LL - 1);
    const int c0 = lane << 2;
    const size_t base = (size_t)nl * CC + c0;

    float4 xc = *(const float4*)&x[base];
    float4 xm = make_float4(0.f, 0.f, 0.f, 0.f);
    float4 xp = make_float4(0.f, 0.f, 0.f, 0.f);
    if (l > 0)      xm = *(const float4*)&x[base - CC];
    if (l < LL - 1) xp = *(const float4*)&x[base + CC];

    float xmv[4] = {xm.x, xm.y, xm.z, xm.w};
    float xcv[4] = {xc.x, xc.y, xc.z, xc.w};
    float xpv[4] = {xp.x, xp.y, xp.z, xp.w};

    float y[4];
    float sum = 0.f, sq = 0.f;
#pragma unroll
    for (int j = 0; j < 4; ++j) {
        const int c = c0 + j;
        float v = fmaf(xmv[j], cw[c * 3 + 0],
                  fmaf(xcv[j], cw[c * 3 + 1],
                  fmaf(xpv[j], cw[c * 3 + 2], cbias[c])));
        y[j] = v;
        sum += v;
        sq  += v * v;
    }
#pragma unroll
    for (int off = 32; off > 0; off >>= 1) {
        sum += __shfl_xor(sum, off);
        sq  += __shfl_xor(sq, off);
    }
    const float mu  = sum * (1.f / CC);
    const float var = sq * (1.f / CC) - mu * mu;
    const float rs  = rsqrtf(var + 1e-6f);

    float o[4];
#pragma unroll
    for (int j = 0; j < 4; ++j) {
        const int c = c0 + j;
        const float tn = (y[j] - mu) * rs * lng[c] + lnb[c];
        o[j] = 0.5f * tn * (1.f + erff(tn * 0.70710678118654752f));
    }
    *(float4*)&xf[base] = make_float4(o[0], o[1], o[2], o[3]);
}

// ---------------------------------------------------------------------------
// K3: offset/mask projection + softmax + bilinear gather-accumulate
// one block per (n, 16 consecutive l). outs may alias xfeat (rows are
// staged to LDS before being overwritten; blocks own disjoint rows).
// ---------------------------------------------------------------------------
__global__ __launch_bounds__(256) void offmask_sample(
    const float* xfeat, const float* __restrict__ xproj,
    const float* __restrict__ Woff, const float* __restrict__ boff,
    const float* __restrict__ Wmask, const float* __restrict__ bmask,
    float* outs)
{
    __shared__ float feat[16][CC];      // 16 KB
    __shared__ float wl[64 * 48];       // 12 KB: W chunk, cols 0-23 off, 24-47 mask
    __shared__ float logit[16 * 48];    // 3 KB
    __shared__ float s_a[384], s_b[384];
    __shared__ int   s_i0[384], s_i1[384];

    const int t = threadIdx.x;
    const int blk = blockIdx.x;
    const int n = blk >> 8;                 // LL/16 = 256 chunks per n
    const int lbase = (blk & 255) << 4;
    const size_t rowbase = ((size_t)n * LL + lbase) * CC;

    // stage 16 rows of x_feat
#pragma unroll
    for (int i = 0; i < 16; ++i)
        feat[i][t] = xfeat[rowbase + (size_t)i * CC + t];

    // each thread owns 3 of the 768 (row,logit) dots
    int lld[3], jjd[3];
    float acc[3] = {0.f, 0.f, 0.f};
#pragma unroll
    for (int d = 0; d < 3; ++d) {
        const int idx = d * 256 + t;
        lld[d] = idx / 48;
        jjd[d] = idx % 48;
    }

    for (int cbk = 0; cbk < 4; ++cbk) {
        __syncthreads();  // covers feat stores (iter 0) and prior wl reads
#pragma unroll
        for (int i = 0; i < 12; ++i) {
            const int e = i * 256 + t;
            const int ccv = e / 48, j = e % 48;
            const int cg = (cbk << 6) + ccv;
            wl[e] = (j < 24) ? Woff[cg * 24 + j] : Wmask[cg * 24 + (j - 24)];
        }
        __syncthreads();
#pragma unroll
        for (int d = 0; d < 3; ++d) {
            const float* fr = &feat[lld[d]][cbk << 6];
            float s = 0.f;
            for (int ccv = 0; ccv < 64; ++ccv)
                s = fmaf(fr[ccv], wl[ccv * 48 + jjd[d]], s);
            acc[d] += s;
        }
    }
#pragma unroll
    for (int d = 0; d < 3; ++d) {
        const int j = jjd[d];
        logit[d * 256 + t] = acc[d] + ((j < 24) ? boff[j] : bmask[j - 24]);
    }
    __syncthreads();

    // softmax over K + sampling locations -> fused weights
    if (t < 128) {
        const int ll = t >> 3, g = t & 7;
        const float* lp = &logit[ll * 48];
        const float m0 = lp[24 + g * 3 + 0];
        const float m1 = lp[24 + g * 3 + 1];
        const float m2 = lp[24 + g * 3 + 2];
        const float mx = fmaxf(m0, fmaxf(m1, m2));
        const float e0 = expf(m0 - mx), e1 = expf(m1 - mx), e2 = expf(m2 - mx);
        const float inv = 1.f / (e0 + e1 + e2);
        const float msk[3] = {e0 * inv, e1 * inv, e2 * inv};
        const float lf = (float)(lbase + ll);
#pragma unroll
        for (int k = 0; k < 3; ++k) {
            const float loc = lf + (float)(k - 1) + lp[g * 3 + k];
            float r = fmodf(loc, (float)LL);
            if (r < 0.f) r += (float)LL;
            const float f0 = floorf(r);
            int i0 = (int)f0;
            i0 = i0 < 0 ? 0 : (i0 > LL - 1 ? LL - 1 : i0);
            const int i1 = i0 + 1;
            const float w1 = r - f0;           // uses unclipped floor, like ref
            const bool valid = (i1 < LL);
            const int idx = (ll * 8 + g) * 3 + k;
            s_a[idx] = msk[k] * (1.f - w1);
            s_b[idx] = valid ? msk[k] * w1 : 0.f;
            s_i0[idx] = i0;
            s_i1[idx] = valid ? i1 : 0;
        }
    }
    __syncthreads();

    // gather-accumulate: thread = channel c
    const int c = t;
    const int g = c >> 5;
    const float* xpb = xproj + (size_t)n * LL * CC;
    for (int i = 0; i < 16; ++i) {
        const int bidx = (i * 8 + g) * 3;
        const float a0 = s_a[bidx + 0], w1b0 = s_b[bidx + 0];
        const float a1 = s_a[bidx + 1], w1b1 = s_b[bidx + 1];
        const float a2 = s_a[bidx + 2], w1b2 = s_b[bidx + 2];
        float v = a0   * xpb[(size_t)s_i0[bidx + 0] * CC + c]
                + w1b0 * xpb[(size_t)s_i1[bidx + 0] * CC + c]
                + a1   * xpb[(size_t)s_i0[bidx + 1] * CC + c]
                + w1b1 * xpb[(size_t)s_i1[bidx + 1] * CC + c]
                + a2   * xpb[(size_t)s_i0[bidx + 2] * CC + c]
                + w1b2 * xpb[(size_t)s_i1[bidx + 2] * CC + c];
        outs[rowbase + (size_t)i * CC + c] = v;
    }
}

// ---------------------------------------------------------------------------
extern "C" void kernel_launch(void* const* d_in, const int* in_sizes, int n_in,
                              void* d_out, int out_size, void* d_ws, size_t ws_size,
                              hipStream_t stream)
{
    const float* x      = (const float*)d_in[0];
    const float* W_in   = (const float*)d_in[1];
    const float* b_in   = (const float*)d_in[2];
    const float* conv_w = (const float*)d_in[3];
    const float* conv_b = (const float*)d_in[4];
    const float* ln_g   = (const float*)d_in[5];
    const float* ln_b   = (const float*)d_in[6];
    const float* W_off  = (const float*)d_in[7];
    const float* b_off  = (const float*)d_in[8];
    const float* W_mask = (const float*)d_in[9];
    const float* b_mask = (const float*)d_in[10];
    const float* W_out  = (const float*)d_in[11];
    const float* b_out  = (const float*)d_in[12];

    // Buffer plan:
    //  x_proj lives in d_out (consumed by K3, then overwritten by final GEMM)
    //  x_feat lives in d_ws (32 MiB); sampled output overwrites it in place
    float* x_proj = (float*)d_out;
    float* x_feat = (float*)d_ws;
    float* out_s  = x_feat;   // safe alias: per-block disjoint rows, LDS-staged
    float* outF   = (float*)d_out;

    gemm_bias<<<dim3(CC / 64, MM / 128), 256, 0, stream>>>(x, W_in, b_in, x_proj);
    conv_ln_gelu<<<dim3(MM / 4), 256, 0, stream>>>(x, conv_w, conv_b, ln_g, ln_b, x_feat);
    offmask_sample<<<dim3(MM / 16), 256, 0, stream>>>(x_feat, x_proj, W_off, b_off,
                                                      W_mask, b_mask, out_s);
    gemm_bias<<<dim3(CC / 64, MM / 128), 256, 0, stream>>>(out_s, W_out, b_out, outF);
}

// Round 2
// 104.904 us; speedup vs baseline: 2.0286x; 2.0286x over previous
//
#include <hip/hip_runtime.h>
#include <math.h>

// Problem constants
constexpr int NB = 8;
constexpr int LL = 4096;
constexpr int CC = 256;
constexpr int GG = 8;
constexpr int MM = NB * LL;  // 32768 rows

typedef unsigned int u32;
typedef unsigned short u16;
typedef __attribute__((ext_vector_type(8))) short bf16x8;
typedef __attribute__((ext_vector_type(4))) float f32x4;

__device__ __forceinline__ u16 f2b(float f) {
    u32 u = __float_as_uint(f);
    u32 r = (u + 0x7fffu + ((u >> 16) & 1u)) >> 16;
    return (u16)r;
}
__device__ __forceinline__ float b2f(u16 h) {
    return __uint_as_float((u32)h << 16);
}

// ---------------------------------------------------------------------------
// prep_w: build bf16 transposed weights.
//   Wt_in[n][k]  = bf16(W_in[k][n]),  Wt_out likewise  (blocks 0..255, n=blk)
//   Wcomb[j][k]  = bf16(j<24 ? W_off[k][j] : W_mask[k][j-24])  (blocks 256..303)
// ---------------------------------------------------------------------------
__global__ __launch_bounds__(256) void prep_w(
    const float* __restrict__ W_in, const float* __restrict__ W_out,
    const float* __restrict__ W_off, const float* __restrict__ W_mask,
    u16* __restrict__ Wt_in, u16* __restrict__ Wt_out, u16* __restrict__ Wcomb)
{
    const int b = blockIdx.x, t = threadIdx.x;
    if (b < 256) {
        Wt_in[b * 256 + t]  = f2b(W_in[t * 256 + b]);
        Wt_out[b * 256 + t] = f2b(W_out[t * 256 + b]);
    } else {
        const int j = b - 256;  // 0..47
        const float v = (j < 24) ? W_off[t * 24 + j] : W_mask[t * 24 + (j - 24)];
        Wcomb[j * 256 + t] = f2b(v);
    }
}

// ---------------------------------------------------------------------------
// gemm_mfma: C[M,256] = A[M,256] @ Bt^T + bias.  Bt is [n][k] bf16.
// Block = 256 thr (4 waves), BM=64, BN=256 (wave w owns cols [w*64,w*64+64)).
// No LDS: MFMA fragments loaded directly from global (L1/L2 absorb re-reads).
// A_FP32: A is fp32, converted to bf16 in-register. OUT_BF16: bf16 C store.
// ---------------------------------------------------------------------------
template<int A_FP32, int OUT_BF16>
__global__ __launch_bounds__(256) void gemm_mfma(
    const void* __restrict__ Ain, const u16* __restrict__ Bt,
    const float* __restrict__ bias, void* __restrict__ Cout)
{
    const int t = threadIdx.x;
    const int w = t >> 6;
    const int lane = t & 63;
    const int lr = lane & 15;
    const int lk8 = (lane >> 4) * 8;     // k element offset of this lane's slice
    const int m0 = blockIdx.x * 64;

    f32x4 acc[4][4];
#pragma unroll
    for (int i = 0; i < 4; ++i)
#pragma unroll
        for (int j = 0; j < 4; ++j) acc[i][j] = f32x4{0.f, 0.f, 0.f, 0.f};

    const u16* Bw = Bt + (size_t)(w * 64) * 256;

#pragma unroll
    for (int ks = 0; ks < 8; ++ks) {
        const int ke = ks * 32 + lk8;
        bf16x8 af[4], bfr[4];
#pragma unroll
        for (int mt = 0; mt < 4; ++mt) {
            const int row = m0 + mt * 16 + lr;
            if (A_FP32) {
                const float* ap = (const float*)Ain + (size_t)row * 256 + ke;
                float4 f0 = *(const float4*)ap;
                float4 f1 = *(const float4*)(ap + 4);
                bf16x8 v;
                v[0] = (short)f2b(f0.x); v[1] = (short)f2b(f0.y);
                v[2] = (short)f2b(f0.z); v[3] = (short)f2b(f0.w);
                v[4] = (short)f2b(f1.x); v[5] = (short)f2b(f1.y);
                v[6] = (short)f2b(f1.z); v[7] = (short)f2b(f1.w);
                af[mt] = v;
            } else {
                af[mt] = *(const bf16x8*)((const u16*)Ain + (size_t)row * 256 + ke);
            }
        }
#pragma unroll
        for (int nt = 0; nt < 4; ++nt)
            bfr[nt] = *(const bf16x8*)(Bw + (size_t)(nt * 16 + lr) * 256 + ke);
#pragma unroll
        for (int mt = 0; mt < 4; ++mt)
#pragma unroll
            for (int nt = 0; nt < 4; ++nt)
                acc[mt][nt] = __builtin_amdgcn_mfma_f32_16x16x32_bf16(
                    af[mt], bfr[nt], acc[mt][nt], 0, 0, 0);
    }

    // Epilogue. D layout (m89-verified): col = lane&15, row = (lane>>4)*4 + reg
    const int r0 = (lane >> 4) * 4;
#pragma unroll
    for (int nt = 0; nt < 4; ++nt) {
        const int cn = w * 64 + nt * 16 + lr;
        const float bv = bias[cn];
#pragma unroll
        for (int mt = 0; mt < 4; ++mt) {
#pragma unroll
            for (int r4 = 0; r4 < 4; ++r4) {
                const int R = m0 + mt * 16 + r0 + r4;
                const float val = acc[mt][nt][r4] + bv;
                if (OUT_BF16) ((u16*)Cout)[(size_t)R * 256 + cn] = f2b(val);
                else          ((float*)Cout)[(size_t)R * 256 + cn] = val;
            }
        }
    }
}

// ---------------------------------------------------------------------------
// conv_ln_gelu: depthwise conv(K=3, zero pad) + LayerNorm(C) + exact GELU.
// One wave per (n,l) row; 4 channels per lane. fp32 math, bf16 output.
// ---------------------------------------------------------------------------
__global__ __launch_bounds__(256) void conv_ln_gelu(
    const float* __restrict__ x, const float* __restrict__ cw,
    const float* __restrict__ cbias, const float* __restrict__ lng,
    const float* __restrict__ lnb, u16* __restrict__ xf)
{
    const int wave = threadIdx.x >> 6;
    const int lane = threadIdx.x & 63;
    const int nl = (blockIdx.x << 2) + wave;
    const int l = nl & (LL - 1);
    const int c0 = lane << 2;
    const size_t base = (size_t)nl * CC + c0;

    float4 xc = *(const float4*)&x[base];
    float4 xm = make_float4(0.f, 0.f, 0.f, 0.f);
    float4 xp = make_float4(0.f, 0.f, 0.f, 0.f);
    if (l > 0)      xm = *(const float4*)&x[base - CC];
    if (l < LL - 1) xp = *(const float4*)&x[base + CC];

    float xmv[4] = {xm.x, xm.y, xm.z, xm.w};
    float xcv[4] = {xc.x, xc.y, xc.z, xc.w};
    float xpv[4] = {xp.x, xp.y, xp.z, xp.w};

    float y[4];
    float sum = 0.f, sq = 0.f;
#pragma unroll
    for (int j = 0; j < 4; ++j) {
        const int c = c0 + j;
        float v = fmaf(xmv[j], cw[c * 3 + 0],
                  fmaf(xcv[j], cw[c * 3 + 1],
                  fmaf(xpv[j], cw[c * 3 + 2], cbias[c])));
        y[j] = v;
        sum += v;
        sq  += v * v;
    }
#pragma unroll
    for (int off = 32; off > 0; off >>= 1) {
        sum += __shfl_xor(sum, off);
        sq  += __shfl_xor(sq, off);
    }
    const float mu  = sum * (1.f / CC);
    const float var = sq * (1.f / CC) - mu * mu;
    const float rs  = rsqrtf(var + 1e-6f);

    ushort4 o;
    float ov[4];
#pragma unroll
    for (int j = 0; j < 4; ++j) {
        const int c = c0 + j;
        const float tn = (y[j] - mu) * rs * lng[c] + lnb[c];
        ov[j] = 0.5f * tn * (1.f + erff(tn * 0.70710678118654752f));
    }
    o.x = f2b(ov[0]); o.y = f2b(ov[1]); o.z = f2b(ov[2]); o.w = f2b(ov[3]);
    *(ushort4*)&xf[base] = o;
}

// ---------------------------------------------------------------------------
// offmask_v2: MFMA offset/mask projection + softmax + bilinear gather.
// Block = 256 thr / 64 rows. Fragments read directly from global.
// outb aliases xfeatb (block reads its feat rows in phase 2, writes phase 4).
// ---------------------------------------------------------------------------
__global__ __launch_bounds__(256) void offmask_v2(
    const u16* __restrict__ xfeatb,   // [32768][256] bf16
    const u16* __restrict__ xprojb,   // [32768][256] bf16
    const u16* __restrict__ Wcomb,    // [48][256] bf16 (j-major)
    const float* __restrict__ boff, const float* __restrict__ bmask,
    u16* __restrict__ outb)           // alias of xfeatb
{
    __shared__ float  logit[64 * 50];     // 12.8 KB, padded stride
    __shared__ float4 s_pack[512 * 3];    // 24 KB: {a, b, i0bits, i1bits}

    const int t = threadIdx.x;
    const int w = t >> 6, lane = t & 63;
    const int lr = lane & 15, lk8 = (lane >> 4) * 8;
    const int blk = blockIdx.x;
    const size_t row0 = (size_t)blk * 64;

    // --- Phase 1+2: MFMA projection, wave w -> rows [w*16, w*16+16), 48 cols
    f32x4 acc[3];
#pragma unroll
    for (int ct = 0; ct < 3; ++ct) acc[ct] = f32x4{0.f, 0.f, 0.f, 0.f};

    const u16* fbase = xfeatb + (row0 + w * 16 + lr) * 256;
#pragma unroll
    for (int ks = 0; ks < 8; ++ks) {
        const int ke = ks * 32 + lk8;
        bf16x8 a = *(const bf16x8*)(fbase + ke);
#pragma unroll
        for (int ct = 0; ct < 3; ++ct) {
            bf16x8 bfr = *(const bf16x8*)(Wcomb + (size_t)(ct * 16 + lr) * 256 + ke);
            acc[ct] = __builtin_amdgcn_mfma_f32_16x16x32_bf16(a, bfr, acc[ct], 0, 0, 0);
        }
    }
    const int r0 = (lane >> 4) * 4;
#pragma unroll
    for (int ct = 0; ct < 3; ++ct) {
        const int j = ct * 16 + lr;
        const float bj = (j < 24) ? boff[j] : bmask[j - 24];
#pragma unroll
        for (int r4 = 0; r4 < 4; ++r4)
            logit[(w * 16 + r0 + r4) * 50 + j] = acc[ct][r4] + bj;
    }
    __syncthreads();

    // --- Phase 3: softmax over K + sampling locations (2 (row,g) pairs/thread)
#pragma unroll
    for (int pi = 0; pi < 2; ++pi) {
        const int pp = pi * 256 + t;        // 0..511
        const int rw = pp >> 3, g = pp & 7;
        const float* lp = &logit[rw * 50];
        const float m0v = lp[24 + g * 3 + 0];
        const float m1v = lp[24 + g * 3 + 1];
        const float m2v = lp[24 + g * 3 + 2];
        const float mx = fmaxf(m0v, fmaxf(m1v, m2v));
        const float e0 = expf(m0v - mx), e1 = expf(m1v - mx), e2 = expf(m2v - mx);
        const float inv = 1.f / (e0 + e1 + e2);
        const float msk[3] = {e0 * inv, e1 * inv, e2 * inv};
        const float lf = (float)((blk & 63) * 64 + rw);  // l within sequence
#pragma unroll
        for (int k = 0; k < 3; ++k) {
            const float loc = lf + (float)(k - 1) + lp[g * 3 + k];
            float r = fmodf(loc, (float)LL);
            if (r < 0.f) r += (float)LL;
            const float f0 = floorf(r);
            int i0 = (int)f0;
            i0 = i0 < 0 ? 0 : (i0 > LL - 1 ? LL - 1 : i0);
            const int i1 = i0 + 1;
            const float w1 = r - f0;
            const bool valid = (i1 < LL);
            s_pack[pp * 3 + k] = make_float4(
                msk[k] * (1.f - w1),
                valid ? msk[k] * w1 : 0.f,
                __int_as_float(i0),
                __int_as_float(valid ? i1 : 0));
        }
    }
    __syncthreads();

    // --- Phase 4: gather-accumulate. thread -> (ihalf, 2 channels)
    const int ihalf = t >> 7, tc = t & 127;
    const int c0 = tc * 2, g4 = tc >> 4;
    const u16* xpn = xprojb + (((size_t)(blk >> 6)) << 12) * 256;  // n base
    const int ibeg = ihalf * 32;
#pragma unroll 4
    for (int i = ibeg; i < ibeg + 32; ++i) {
        const int bidx = (i * 8 + g4) * 3;
        float ve = 0.f, vo = 0.f;
#pragma unroll
        for (int k = 0; k < 3; ++k) {
            const float4 pk = s_pack[bidx + k];
            const int i0 = __float_as_int(pk.z), i1 = __float_as_int(pk.w);
            const u32 u0 = *(const u32*)(xpn + (size_t)i0 * 256 + c0);
            const u32 u1 = *(const u32*)(xpn + (size_t)i1 * 256 + c0);
            ve = fmaf(pk.x, __uint_as_float(u0 << 16),
                 fmaf(pk.y, __uint_as_float(u1 << 16), ve));
            vo = fmaf(pk.x, __uint_as_float(u0 & 0xffff0000u),
                 fmaf(pk.y, __uint_as_float(u1 & 0xffff0000u), vo));
        }
        const u32 o = (u32)f2b(ve) | ((u32)f2b(vo) << 16);
        *(u32*)(outb + (row0 + i) * 256 + c0) = o;
    }
}

// ---------------------------------------------------------------------------
extern "C" void kernel_launch(void* const* d_in, const int* in_sizes, int n_in,
                              void* d_out, int out_size, void* d_ws, size_t ws_size,
                              hipStream_t stream)
{
    const float* x      = (const float*)d_in[0];
    const float* W_in   = (const float*)d_in[1];
    const float* b_in   = (const float*)d_in[2];
    const float* conv_w = (const float*)d_in[3];
    const float* conv_b = (const float*)d_in[4];
    const float* ln_g   = (const float*)d_in[5];
    const float* ln_b   = (const float*)d_in[6];
    const float* W_off  = (const float*)d_in[7];
    const float* b_off  = (const float*)d_in[8];
    const float* W_mask = (const float*)d_in[9];
    const float* b_mask = (const float*)d_in[10];
    const float* W_out  = (const float*)d_in[11];
    const float* b_out  = (const float*)d_in[12];

    // ws layout (<= 17.1 MB, round-1 proved >= 32 MiB):
    //   [0, 16M)         x_feat bf16, later overwritten in-place by sampled bf16
    //   [16M, +131072)   Wt_in bf16   [n][k]
    //   [.., +131072)    Wt_out bf16  [n][k]
    //   [.., +24576)     Wcomb bf16   [48][256]
    u16* xfeatb = (u16*)d_ws;
    char* wsb   = (char*)d_ws + 16777216;
    u16* Wt_in  = (u16*)(wsb);
    u16* Wt_out = (u16*)(wsb + 131072);
    u16* Wcombp = (u16*)(wsb + 262144);
    // xproj bf16 lives in the lower 16 MB of d_out (fp32 final output written
    // only by the last GEMM, which doesn't read d_out).
    u16* xprojb = (u16*)d_out;
    u16* sampb  = xfeatb;  // in-place alias (per-block disjoint rows)

    prep_w<<<304, 256, 0, stream>>>(W_in, W_out, W_off, W_mask, Wt_in, Wt_out, Wcombp);
    gemm_mfma<1, 1><<<MM / 64, 256, 0, stream>>>(x, Wt_in, b_in, xprojb);
    conv_ln_gelu<<<MM / 4, 256, 0, stream>>>(x, conv_w, conv_b, ln_g, ln_b, xfeatb);
    offmask_v2<<<MM / 64, 256, 0, stream>>>(xfeatb, xprojb, Wcombp, b_off, b_mask, sampb);
    gemm_mfma<0, 0><<<MM / 64, 256, 0, stream>>>(sampb, Wt_out, b_out, (float*)d_out);
}

// Round 3
// 90.148 us; speedup vs baseline: 2.3606x; 1.1637x over previous
//
#include <hip/hip_runtime.h>
#include <math.h>

// Problem constants
constexpr int NB = 8;
constexpr int LL = 4096;
constexpr int CC = 256;
constexpr int MM = NB * LL;  // 32768 rows

typedef unsigned int u32;
typedef unsigned short u16;
typedef __attribute__((ext_vector_type(8))) short bf16x8;
typedef __attribute__((ext_vector_type(4))) float f32x4;

__device__ __forceinline__ u16 f2b(float f) {
    u32 u = __float_as_uint(f);
    u32 r = (u + 0x7fffu + ((u >> 16) & 1u)) >> 16;
    return (u16)r;
}

// ---------------------------------------------------------------------------
// prep_w: bf16 transposed weights.
//   blocks 0..255:  Wt_in[n][k] = bf16(W_in[k][n]); Wt_out likewise
//   blocks 256..303: Wcomb[j][k] = bf16(j<24 ? W_off[k][j] : W_mask[k][j-24])
// ---------------------------------------------------------------------------
__global__ __launch_bounds__(256) void prep_w(
    const float* __restrict__ W_in, const float* __restrict__ W_out,
    const float* __restrict__ W_off, const float* __restrict__ W_mask,
    u16* __restrict__ Wt_in, u16* __restrict__ Wt_out, u16* __restrict__ Wcomb)
{
    const int b = blockIdx.x, t = threadIdx.x;
    if (b < 256) {
        Wt_in[b * 256 + t]  = f2b(W_in[t * 256 + b]);
        Wt_out[b * 256 + t] = f2b(W_out[t * 256 + b]);
    } else {
        const int j = b - 256;  // 0..47
        const float v = (j < 24) ? W_off[t * 24 + j] : W_mask[t * 24 + (j - 24)];
        Wcomb[j * 256 + t] = f2b(v);
    }
}

// ---------------------------------------------------------------------------
// proj_conv: fused { x_proj = x@W_in+b_in (MFMA, bf16 out) } +
//            { depthwise conv(K=3) + LayerNorm + exact GELU (bf16 out) }.
// One block = 64 rows; x is read once from HBM (conv re-reads are L1/L2 hot).
// ---------------------------------------------------------------------------
__global__ __launch_bounds__(256) void proj_conv(
    const float* __restrict__ x, const u16* __restrict__ Wt_in,
    const float* __restrict__ b_in,
    const float* __restrict__ cw, const float* __restrict__ cbias,
    const float* __restrict__ lng, const float* __restrict__ lnb,
    u16* __restrict__ xprojb, u16* __restrict__ xfeatb)
{
    const int t = threadIdx.x;
    const int w = t >> 6;
    const int lane = t & 63;
    const int lr = lane & 15;
    const int lk8 = (lane >> 4) * 8;
    const int m0 = blockIdx.x * 64;

    // ---- Phase 1: GEMM tile 64x256, wave w owns cols [w*64, w*64+64)
    f32x4 acc[4][4];
#pragma unroll
    for (int i = 0; i < 4; ++i)
#pragma unroll
        for (int j = 0; j < 4; ++j) acc[i][j] = f32x4{0.f, 0.f, 0.f, 0.f};

    const u16* Bw = Wt_in + (size_t)(w * 64) * 256;
#pragma unroll
    for (int ks = 0; ks < 8; ++ks) {
        const int ke = ks * 32 + lk8;
        bf16x8 af[4], bfr[4];
#pragma unroll
        for (int mt = 0; mt < 4; ++mt) {
            const float* ap = x + (size_t)(m0 + mt * 16 + lr) * 256 + ke;
            float4 f0 = *(const float4*)ap;
            float4 f1 = *(const float4*)(ap + 4);
            bf16x8 v;
            v[0] = (short)f2b(f0.x); v[1] = (short)f2b(f0.y);
            v[2] = (short)f2b(f0.z); v[3] = (short)f2b(f0.w);
            v[4] = (short)f2b(f1.x); v[5] = (short)f2b(f1.y);
            v[6] = (short)f2b(f1.z); v[7] = (short)f2b(f1.w);
            af[mt] = v;
        }
#pragma unroll
        for (int nt = 0; nt < 4; ++nt)
            bfr[nt] = *(const bf16x8*)(Bw + (size_t)(nt * 16 + lr) * 256 + ke);
#pragma unroll
        for (int mt = 0; mt < 4; ++mt)
#pragma unroll
            for (int nt = 0; nt < 4; ++nt)
                acc[mt][nt] = __builtin_amdgcn_mfma_f32_16x16x32_bf16(
                    af[mt], bfr[nt], acc[mt][nt], 0, 0, 0);
    }
    const int r0 = (lane >> 4) * 4;
#pragma unroll
    for (int nt = 0; nt < 4; ++nt) {
        const int cn = w * 64 + nt * 16 + lr;
        const float bv = b_in[cn];
#pragma unroll
        for (int mt = 0; mt < 4; ++mt)
#pragma unroll
            for (int r4 = 0; r4 < 4; ++r4)
                xprojb[(size_t)(m0 + mt * 16 + r0 + r4) * 256 + cn] =
                    f2b(acc[mt][nt][r4] + bv);
    }

    // ---- Phase 2: conv + LN + GELU, wave w -> rows [w*16, w*16+16)
    const int l0 = m0 & (LL - 1);
    const int c0 = lane << 2;
    const int rbase = w * 16;
    const int lw = l0 + rbase;

    float4 zero = make_float4(0.f, 0.f, 0.f, 0.f);
    float4 cur  = *(const float4*)&x[(size_t)(m0 + rbase) * 256 + c0];
    float4 prev = (lw > 0) ? *(const float4*)&x[(size_t)(m0 + rbase - 1) * 256 + c0]
                           : zero;
    const float cw0[4] = {cw[(c0+0)*3+0], cw[(c0+1)*3+0], cw[(c0+2)*3+0], cw[(c0+3)*3+0]};
    const float cw1[4] = {cw[(c0+0)*3+1], cw[(c0+1)*3+1], cw[(c0+2)*3+1], cw[(c0+3)*3+1]};
    const float cw2[4] = {cw[(c0+0)*3+2], cw[(c0+1)*3+2], cw[(c0+2)*3+2], cw[(c0+3)*3+2]};
    const float cb4[4] = {cbias[c0+0], cbias[c0+1], cbias[c0+2], cbias[c0+3]};
    const float lg4[4] = {lng[c0+0], lng[c0+1], lng[c0+2], lng[c0+3]};
    const float lb4[4] = {lnb[c0+0], lnb[c0+1], lnb[c0+2], lnb[c0+3]};

    for (int i = 0; i < 16; ++i) {
        const int l = lw + i;
        float4 nxt = (l < LL - 1)
            ? *(const float4*)&x[(size_t)(m0 + rbase + i + 1) * 256 + c0] : zero;
        float pv[4] = {prev.x, prev.y, prev.z, prev.w};
        float cv[4] = {cur.x, cur.y, cur.z, cur.w};
        float nv[4] = {nxt.x, nxt.y, nxt.z, nxt.w};
        float y[4];
        float sum = 0.f, sq = 0.f;
#pragma unroll
        for (int j = 0; j < 4; ++j) {
            float v = fmaf(pv[j], cw0[j], fmaf(cv[j], cw1[j],
                      fmaf(nv[j], cw2[j], cb4[j])));
            y[j] = v; sum += v; sq += v * v;
        }
#pragma unroll
        for (int off = 32; off > 0; off >>= 1) {
            sum += __shfl_xor(sum, off);
            sq  += __shfl_xor(sq, off);
        }
        const float mu  = sum * (1.f / CC);
        const float var = sq * (1.f / CC) - mu * mu;
        const float rs  = rsqrtf(var + 1e-6f);
        ushort4 o;
        float ov[4];
#pragma unroll
        for (int j = 0; j < 4; ++j) {
            const float tn = (y[j] - mu) * rs * lg4[j] + lb4[j];
            ov[j] = 0.5f * tn * (1.f + erff(tn * 0.70710678118654752f));
        }
        o.x = f2b(ov[0]); o.y = f2b(ov[1]); o.z = f2b(ov[2]); o.w = f2b(ov[3]);
        *(ushort4*)&xfeatb[(size_t)(m0 + rbase + i) * 256 + c0] = o;
        prev = cur; cur = nxt;
    }
}

// ---------------------------------------------------------------------------
// offmask_gemm: fused { offset/mask MFMA projection + softmax + bilinear
// gather -> LDS } + { final GEMM sampled@W_out + b_out -> fp32 out }.
// Block = 64 rows, 256 thr. LDS union: logit (12.8KB) reused as sampled
// 64x256 bf16 tile (32KB, XOR-swizzled); s_pack 24KB separate. Total 56KB.
// ---------------------------------------------------------------------------
__global__ __launch_bounds__(256) void offmask_gemm(
    const u16* __restrict__ xfeatb, const u16* __restrict__ xprojb,
    const u16* __restrict__ Wcomb, const float* __restrict__ boff,
    const float* __restrict__ bmask, const u16* __restrict__ Wt_out,
    const float* __restrict__ b_out, float* __restrict__ out)
{
    __shared__ __align__(16) char s_mem[32768];   // logit then sampled (union)
    __shared__ float4 s_pack[512 * 3];            // {a, b, i0bits, i1bits}
    float* logit = (float*)s_mem;                 // [64][50]

    const int t = threadIdx.x;
    const int w = t >> 6, lane = t & 63;
    const int lr = lane & 15, lk8 = (lane >> 4) * 8;
    const int r0 = (lane >> 4) * 4;
    const int blk = blockIdx.x;
    const size_t row0 = (size_t)blk * 64;

    // --- Phase 1: projection MFMA -> logits (48 cols per row)
    f32x4 pacc[3];
#pragma unroll
    for (int ct = 0; ct < 3; ++ct) pacc[ct] = f32x4{0.f, 0.f, 0.f, 0.f};
    const u16* fbase = xfeatb + (row0 + w * 16 + lr) * 256;
#pragma unroll
    for (int ks = 0; ks < 8; ++ks) {
        const int ke = ks * 32 + lk8;
        bf16x8 a = *(const bf16x8*)(fbase + ke);
#pragma unroll
        for (int ct = 0; ct < 3; ++ct) {
            bf16x8 bfr = *(const bf16x8*)(Wcomb + (size_t)(ct * 16 + lr) * 256 + ke);
            pacc[ct] = __builtin_amdgcn_mfma_f32_16x16x32_bf16(a, bfr, pacc[ct], 0, 0, 0);
        }
    }
#pragma unroll
    for (int ct = 0; ct < 3; ++ct) {
        const int j = ct * 16 + lr;
        const float bj = (j < 24) ? boff[j] : bmask[j - 24];
#pragma unroll
        for (int r4 = 0; r4 < 4; ++r4)
            logit[(w * 16 + r0 + r4) * 50 + j] = pacc[ct][r4] + bj;
    }
    __syncthreads();

    // --- Phase 2: softmax over K + locations (2 (row,g) pairs per thread)
#pragma unroll
    for (int pi = 0; pi < 2; ++pi) {
        const int pp = pi * 256 + t;        // 0..511
        const int rw = pp >> 3, g = pp & 7;
        const float* lp = &logit[rw * 50];
        const float m0v = lp[24 + g * 3 + 0];
        const float m1v = lp[24 + g * 3 + 1];
        const float m2v = lp[24 + g * 3 + 2];
        const float mx = fmaxf(m0v, fmaxf(m1v, m2v));
        const float e0 = expf(m0v - mx), e1 = expf(m1v - mx), e2 = expf(m2v - mx);
        const float inv = 1.f / (e0 + e1 + e2);
        const float msk[3] = {e0 * inv, e1 * inv, e2 * inv};
        const float lf = (float)((blk & 63) * 64 + rw);
#pragma unroll
        for (int k = 0; k < 3; ++k) {
            const float loc = lf + (float)(k - 1) + lp[g * 3 + k];
            float r = fmodf(loc, (float)LL);
            if (r < 0.f) r += (float)LL;
            const float f0 = floorf(r);
            int i0 = (int)f0;
            i0 = i0 < 0 ? 0 : (i0 > LL - 1 ? LL - 1 : i0);
            const int i1 = i0 + 1;
            const float w1 = r - f0;
            const bool valid = (i1 < LL);
            s_pack[pp * 3 + k] = make_float4(
                msk[k] * (1.f - w1),
                valid ? msk[k] * w1 : 0.f,
                __int_as_float(i0),
                __int_as_float(valid ? i1 : 0));
        }
    }
    __syncthreads();   // logit reads done; s_mem can be reused as sampled tile

    // --- Phase 3: gather-accumulate -> sampled bf16 tile in LDS (swizzled)
    {
        const int ihalf = t >> 7, tc = t & 127;
        const int c0 = tc * 2, g4 = tc >> 4;
        const u16* xpn = xprojb + (((size_t)(blk >> 6)) << 12) * 256;
        const int ibeg = ihalf * 32;
#pragma unroll 4
        for (int i = ibeg; i < ibeg + 32; ++i) {
            const int bidx = (i * 8 + g4) * 3;
            float ve = 0.f, vo = 0.f;
#pragma unroll
            for (int k = 0; k < 3; ++k) {
                const float4 pk = s_pack[bidx + k];
                const int i0 = __float_as_int(pk.z), i1 = __float_as_int(pk.w);
                const u32 u0 = *(const u32*)(xpn + (size_t)i0 * 256 + c0);
                const u32 u1 = *(const u32*)(xpn + (size_t)i1 * 256 + c0);
                ve = fmaf(pk.x, __uint_as_float(u0 << 16),
                     fmaf(pk.y, __uint_as_float(u1 << 16), ve));
                vo = fmaf(pk.x, __uint_as_float(u0 & 0xffff0000u),
                     fmaf(pk.y, __uint_as_float(u1 & 0xffff0000u), vo));
            }
            const u32 word = (u32)f2b(ve) | ((u32)f2b(vo) << 16);
            const int addr = (i * 512 + tc * 4) ^ ((i & 7) << 4);
            *(u32*)(s_mem + addr) = word;
        }
    }
    __syncthreads();

    // --- Phase 4: final GEMM from LDS tile, wave w -> cols [w*64, w*64+64)
    f32x4 acc[4][4];
#pragma unroll
    for (int i = 0; i < 4; ++i)
#pragma unroll
        for (int j = 0; j < 4; ++j) acc[i][j] = f32x4{0.f, 0.f, 0.f, 0.f};

    const u16* Bw = Wt_out + (size_t)(w * 64) * 256;
#pragma unroll
    for (int ks = 0; ks < 8; ++ks) {
        bf16x8 af[4], bfr[4];
#pragma unroll
        for (int mt = 0; mt < 4; ++mt) {
            const int rm = mt * 16 + lr;
            const int addr = (rm * 512 + ks * 64 + lk8 * 2) ^ ((rm & 7) << 4);
            af[mt] = *(const bf16x8*)(s_mem + addr);
        }
        const int ke = ks * 32 + lk8;
#pragma unroll
        for (int nt = 0; nt < 4; ++nt)
            bfr[nt] = *(const bf16x8*)(Bw + (size_t)(nt * 16 + lr) * 256 + ke);
#pragma unroll
        for (int mt = 0; mt < 4; ++mt)
#pragma unroll
            for (int nt = 0; nt < 4; ++nt)
                acc[mt][nt] = __builtin_amdgcn_mfma_f32_16x16x32_bf16(
                    af[mt], bfr[nt], acc[mt][nt], 0, 0, 0);
    }
#pragma unroll
    for (int nt = 0; nt < 4; ++nt) {
        const int cn = w * 64 + nt * 16 + lr;
        const float bv = b_out[cn];
#pragma unroll
        for (int mt = 0; mt < 4; ++mt)
#pragma unroll
            for (int r4 = 0; r4 < 4; ++r4)
                out[(row0 + mt * 16 + r0 + r4) * 256 + cn] = acc[mt][nt][r4] + bv;
    }
}

// ---------------------------------------------------------------------------
extern "C" void kernel_launch(void* const* d_in, const int* in_sizes, int n_in,
                              void* d_out, int out_size, void* d_ws, size_t ws_size,
                              hipStream_t stream)
{
    const float* x      = (const float*)d_in[0];
    const float* W_in   = (const float*)d_in[1];
    const float* b_in   = (const float*)d_in[2];
    const float* conv_w = (const float*)d_in[3];
    const float* conv_b = (const float*)d_in[4];
    const float* ln_g   = (const float*)d_in[5];
    const float* ln_b   = (const float*)d_in[6];
    const float* W_off  = (const float*)d_in[7];
    const float* b_off  = (const float*)d_in[8];
    const float* W_mask = (const float*)d_in[9];
    const float* b_mask = (const float*)d_in[10];
    const float* W_out  = (const float*)d_in[11];
    const float* b_out  = (const float*)d_in[12];

    // ws layout (~33.9 MB; ws is 256 MiB per the fillBuffer WRITE_SIZE=256MiB):
    //   [0, 16M)      x_feat bf16 [32768][256]
    //   [16M, 32M)    x_proj bf16 [32768][256]
    //   [32M, ...)    Wt_in (128K), Wt_out (128K), Wcomb (24K)
    u16* xfeatb = (u16*)d_ws;
    u16* xprojb = (u16*)((char*)d_ws + 16777216);
    char* wsb   = (char*)d_ws + 33554432;
    u16* Wt_in  = (u16*)(wsb);
    u16* Wt_out = (u16*)(wsb + 131072);
    u16* Wcombp = (u16*)(wsb + 262144);

    prep_w<<<304, 256, 0, stream>>>(W_in, W_out, W_off, W_mask, Wt_in, Wt_out, Wcombp);
    proj_conv<<<MM / 64, 256, 0, stream>>>(x, Wt_in, b_in, conv_w, conv_b,
                                           ln_g, ln_b, xprojb, xfeatb);
    offmask_gemm<<<MM / 64, 256, 0, stream>>>(xfeatb, xprojb, Wcombp, b_off, b_mask,
                                              Wt_out, b_out, (float*)d_out);
}